// Round 7
// baseline (1306.468 us; speedup 1.0000x reference)
//
#include <hip/hip_runtime.h>

#define B_ 64
#define S_ 512
#define D_ 256
#define H_ 128
#define M_ 64
#define N_ (B_ * S_)                 // 32768 nodes
#define YSZ ((size_t)N_ * H_)        // 4194304 floats
#define ADJSZ ((size_t)B_ * S_ * S_) // 16777216 floats

typedef __attribute__((ext_vector_type(8))) _Float16 f16x8;
typedef __attribute__((ext_vector_type(2))) _Float16 h2;
typedef __attribute__((ext_vector_type(4))) float f32x4;

#define MFMAH(a, b, c) __builtin_amdgcn_mfma_f32_16x16x32_f16(a, b, c, 0, 0, 0)

// weight frag store: 8 n-tiles x 14 k-chunks, 64 lanes x 16B each (f16)
#define WFRAGS (8 * 14)
#define WBYTES ((size_t)WFRAGS * 64 * 16)  // 114688

__device__ __forceinline__ float fast_tanh(float x) {
  float cx = __builtin_amdgcn_fmed3f(x, -10.0f, 10.0f);
  float e = __builtin_amdgcn_exp2f(cx * 2.8853900817779268f);
  float r = __builtin_amdgcn_rcpf(e + 1.0f);
  return fmaf(-2.0f, r, 1.0f);
}
__device__ __forceinline__ float fast_sigmoid(float x) {
  float cx = __builtin_amdgcn_fmed3f(x, -30.0f, 30.0f);
  float e = __builtin_amdgcn_exp2f(cx * -1.4426950408889634f);
  return __builtin_amdgcn_rcpf(1.0f + e);
}

// element index in a [rows][Kc] f16 array, XOR-swizzled 16B (8-elem) granules
__device__ __forceinline__ int sw(int row, int col, int Kc) {
  return row * Kc + ((((col >> 3) ^ (row & 7)) << 3) | (col & 7));
}

// ---------------------------------------------------------------- zero adj
__global__ void kzero(float4* __restrict__ p, int n4) {
  int i = blockIdx.x * blockDim.x + threadIdx.x;
  int stride = gridDim.x * blockDim.x;
  float4 z = {0.f, 0.f, 0.f, 0.f};
  for (; i < n4; i += stride) p[i] = z;
}

// ---------------- K0: pack f16 weight fragments (native MFMA B-frag order)
__global__ __launch_bounds__(256) void k0_prep(
    const float* __restrict__ eWih0, const float* __restrict__ eWhh0,
    const float* __restrict__ eWih1, const float* __restrict__ eWhh1,
    unsigned short* __restrict__ Wf) {
  int t = blockIdx.x * 256 + threadIdx.x;
  if (t >= WFRAGS * 64) return;
  int fid = t >> 6, lane = t & 63;
  int ntg = fid / 14, kc = fid % 14;
  int j = ntg * 16 + (lane & 15);
  int kbase = (kc < 6 ? kc : kc - 6) * 32 + (lane >> 4) * 8;
  unsigned pk[4];
#pragma unroll
  for (int ii = 0; ii < 4; ++ii) {
    unsigned p2 = 0;
#pragma unroll
    for (int s = 0; s < 2; ++s) {
      int k = kbase + ii * 2 + s;
      float wv;
      if (kc < 6)
        wv = (k < 64) ? eWih0[j * 64 + k] : eWhh0[j * 128 + (k - 64)];
      else
        wv = (k < 128) ? eWih1[j * 128 + k] : eWhh1[j * 128 + (k - 128)];
      _Float16 h = (_Float16)wv;
      unsigned short us = *(unsigned short*)&h;
      p2 |= ((unsigned)us) << (16 * s);
    }
    pk[ii] = p2;
  }
  ((uint4*)Wf)[fid * 64 + lane] = make_uint4(pk[0], pk[1], pk[2], pk[3]);
}

// ------------------------------------------- K1: P0 = x @ Wih0^T + (bih0+bhh0)
__global__ __launch_bounds__(256) void k1_gemm(
    const float* __restrict__ x, const float* __restrict__ W,
    const float* __restrict__ bih, const float* __restrict__ bhh,
    float* __restrict__ P0) {
  __shared__ float Xs[32][132];
  __shared__ float Ws[32][132];
  const int t = threadIdx.x;
  const int ty = t >> 4, tx = t & 15;
  const int n0 = blockIdx.x * 128;
  float acc[8][8];
#pragma unroll
  for (int i = 0; i < 8; ++i)
#pragma unroll
    for (int j = 0; j < 8; ++j) acc[i][j] = 0.f;

  for (int kc = 0; kc < 256; kc += 32) {
    __syncthreads();
#pragma unroll
    for (int l = 0; l < 4; ++l) {
      int idx = t + l * 256;
      int r = idx >> 3, f4 = idx & 7;
      float4 v = *(const float4*)&x[(size_t)(n0 + r) * 256 + kc + f4 * 4];
      Xs[f4 * 4 + 0][r] = v.x; Xs[f4 * 4 + 1][r] = v.y;
      Xs[f4 * 4 + 2][r] = v.z; Xs[f4 * 4 + 3][r] = v.w;
      float4 wv = *(const float4*)&W[(size_t)r * 256 + kc + f4 * 4];
      Ws[f4 * 4 + 0][r] = wv.x; Ws[f4 * 4 + 1][r] = wv.y;
      Ws[f4 * 4 + 2][r] = wv.z; Ws[f4 * 4 + 3][r] = wv.w;
    }
    __syncthreads();
#pragma unroll
    for (int kk = 0; kk < 32; ++kk) {
      float4 xa = *(const float4*)&Xs[kk][ty * 8];
      float4 xb = *(const float4*)&Xs[kk][ty * 8 + 4];
      float4 wa = *(const float4*)&Ws[kk][tx * 8];
      float4 wb = *(const float4*)&Ws[kk][tx * 8 + 4];
      float xr[8] = {xa.x, xa.y, xa.z, xa.w, xb.x, xb.y, xb.z, xb.w};
      float wr[8] = {wa.x, wa.y, wa.z, wa.w, wb.x, wb.y, wb.z, wb.w};
#pragma unroll
      for (int i = 0; i < 8; ++i)
#pragma unroll
        for (int j = 0; j < 8; ++j) acc[i][j] += xr[i] * wr[j];
    }
  }
  float bias[8];
#pragma unroll
  for (int j = 0; j < 8; ++j) bias[j] = bih[tx * 8 + j] + bhh[tx * 8 + j];
#pragma unroll
  for (int i = 0; i < 8; ++i) {
    float4 s0 = make_float4(acc[i][0] + bias[0], acc[i][1] + bias[1],
                            acc[i][2] + bias[2], acc[i][3] + bias[3]);
    float4 s1 = make_float4(acc[i][4] + bias[4], acc[i][5] + bias[5],
                            acc[i][6] + bias[6], acc[i][7] + bias[7]);
    size_t base = (size_t)(n0 + ty * 8 + i) * 128 + tx * 8;
    *(float4*)&P0[base] = s0;
    *(float4*)&P0[base + 4] = s1;
  }
}

// ------------------------- K2 v5: graph RNN, 8 waves, lane-pair k-split,
// register-resident weights + 8-DEEP P0/mask prefetch (unroll-by-8, static
// rotating regs -> counted-vmcnt pipeline; HBM latency off the chain).
// Mask folded into the Y store (kmask kernel eliminated).
__global__ __launch_bounds__(512, 2) void k2_v5(
    const float* __restrict__ P0, const float* __restrict__ Whh0,
    const float* __restrict__ Wih1, const float* __restrict__ Whh1,
    const float* __restrict__ bih1, const float* __restrict__ bhh1,
    const int* __restrict__ mask, float* __restrict__ Y) {
  __shared__ __align__(16) float r0f[2][128];
  __shared__ __align__(16) float r1f[2][128];
  __shared__ __align__(16) _Float16 r0h[2][128];
  const int tid = threadIdx.x;
  const int g = tid & 255;
  const bool isL0 = (tid < 256);
  const int row = g >> 1;
  const int half = g & 1;
  const int kb = half * 64;
  const int b = blockIdx.x;

  float4 Wa4[16];
  {
    const float* src = (isL0 ? Whh0 : Whh1) + row * 128 + kb;
#pragma unroll
    for (int i = 0; i < 16; ++i) Wa4[i] = *(const float4*)&src[i * 4];
  }
  h2 Wb2[32];
  if (!isL0) {
    const float* s2 = Wih1 + row * 128 + kb;
#pragma unroll
    for (int i = 0; i < 32; ++i) {
      h2 t;
      t.x = (_Float16)s2[i * 2];
      t.y = (_Float16)s2[i * 2 + 1];
      Wb2[i] = t;
    }
  }
  const float b1c = (!isL0 && half == 0) ? (bih1[row] + bhh1[row]) : 0.f;
  if (tid < 128) { r0f[1][tid] = 0.f; r1f[0][tid] = 0.f; }

  // 8-deep prefetch registers (static indices only — must stay in VGPRs)
  float pp[8];  // L0/half0: P0[b][s][row], slot = s & 7
  float mm[8];  // L1/half1: mask[b][t] as float, slot = t & 7
  if (isL0 && half == 0) {
#pragma unroll
    for (int u = 0; u < 8; ++u) pp[u] = P0[((size_t)b * 512 + u) * 128 + row];
  }
  if (!isL0 && half == 1) {
#pragma unroll
    for (int u = 0; u < 8; ++u) mm[u] = (float)mask[b * 512 + u];
  }
  __syncthreads();

  for (int so = 0; so < 512; so += 8) {
#pragma unroll
    for (int u = 0; u < 8; ++u) {
      const int s = so + u;
      const int cs = u & 1, ps = cs ^ 1;  // s&1 == u&1 (so % 8 == 0)
      if (isL0) {
        float a0 = (half == 0) ? pp[u] : 0.f;  // L0 bias folded into P0
        float a1 = 0.f, a2 = 0.f, a3 = 0.f;
        const float4* hp = (const float4*)&r0f[ps][kb];
#pragma unroll
        for (int c = 0; c < 4; ++c) {
          float4 h0v = hp[c * 4 + 0], h1v = hp[c * 4 + 1];
          float4 h2v = hp[c * 4 + 2], h3v = hp[c * 4 + 3];
          float4 w0 = Wa4[c * 4 + 0], w1 = Wa4[c * 4 + 1];
          float4 w2 = Wa4[c * 4 + 2], w3 = Wa4[c * 4 + 3];
          a0 += w0.x * h0v.x + w0.y * h0v.y + w0.z * h0v.z + w0.w * h0v.w;
          a1 += w1.x * h1v.x + w1.y * h1v.y + w1.z * h1v.z + w1.w * h1v.w;
          a2 += w2.x * h2v.x + w2.y * h2v.y + w2.z * h2v.z + w2.w * h2v.w;
          a3 += w3.x * h3v.x + w3.y * h3v.y + w3.z * h3v.z + w3.w * h3v.w;
        }
        float acc = (a0 + a1) + (a2 + a3);
        acc += __shfl_xor(acc, 1);
        float y = fast_tanh(acc);
        if (half == 0) {
          r0f[cs][row] = y;
          // reissue slot u for step s+8 (clamped; surplus loads harmless)
          int sn = (s + 8 < 512) ? s + 8 : 511;
          pp[u] = P0[((size_t)b * 512 + sn) * 128 + row];
        } else {
          r0h[cs][row] = (_Float16)y;
        }
      } else {
        if (u > 0 || so > 0) {
          const int t = s - 1;
          float a0 = b1c, a1 = 0.f, a2 = 0.f, a3 = 0.f;
          const uint2* yp = (const uint2*)&r0h[ps][kb];
#pragma unroll
          for (int c = 0; c < 8; ++c) {
            uint2 uu = yp[c * 2 + 0];
            uint2 vv = yp[c * 2 + 1];
            h2 x0 = __builtin_bit_cast(h2, uu.x);
            h2 x1 = __builtin_bit_cast(h2, uu.y);
            h2 x2 = __builtin_bit_cast(h2, vv.x);
            h2 x3 = __builtin_bit_cast(h2, vv.y);
#if __has_builtin(__builtin_amdgcn_fdot2)
            a0 = __builtin_amdgcn_fdot2(Wb2[c * 4 + 0], x0, a0, false);
            a1 = __builtin_amdgcn_fdot2(Wb2[c * 4 + 1], x1, a1, false);
            a2 = __builtin_amdgcn_fdot2(Wb2[c * 4 + 2], x2, a2, false);
            a3 = __builtin_amdgcn_fdot2(Wb2[c * 4 + 3], x3, a3, false);
#else
            a0 += (float)Wb2[c * 4 + 0].x * (float)x0.x +
                  (float)Wb2[c * 4 + 0].y * (float)x0.y;
            a1 += (float)Wb2[c * 4 + 1].x * (float)x1.x +
                  (float)Wb2[c * 4 + 1].y * (float)x1.y;
            a2 += (float)Wb2[c * 4 + 2].x * (float)x2.x +
                  (float)Wb2[c * 4 + 2].y * (float)x2.y;
            a3 += (float)Wb2[c * 4 + 3].x * (float)x3.x +
                  (float)Wb2[c * 4 + 3].y * (float)x3.y;
#endif
          }
          const float4* hp = (const float4*)&r1f[ps][kb];
#pragma unroll
          for (int c = 0; c < 4; ++c) {
            float4 h0v = hp[c * 4 + 0], h1v = hp[c * 4 + 1];
            float4 h2v = hp[c * 4 + 2], h3v = hp[c * 4 + 3];
            float4 w0 = Wa4[c * 4 + 0], w1 = Wa4[c * 4 + 1];
            float4 w2 = Wa4[c * 4 + 2], w3 = Wa4[c * 4 + 3];
            a0 += w0.x * h0v.x + w0.y * h0v.y + w0.z * h0v.z + w0.w * h0v.w;
            a1 += w1.x * h1v.x + w1.y * h1v.y + w1.z * h1v.z + w1.w * h1v.w;
            a2 += w2.x * h2v.x + w2.y * h2v.y + w2.z * h2v.z + w2.w * h2v.w;
            a3 += w3.x * h3v.x + w3.y * h3v.y + w3.z * h3v.z + w3.w * h3v.w;
          }
          float acc = (a0 + a1) + (a2 + a3);
          acc += __shfl_xor(acc, 1);
          float y = fast_tanh(acc);
          if (half == 0) {
            r1f[cs][row] = y;
          } else {
            const int slot = (u == 0) ? 7 : (u - 1);  // t & 7, static
            Y[((size_t)b * 512 + t) * 128 + row] = y * mm[slot];
            int tn = (t + 8 < 512) ? t + 8 : 511;
            mm[slot] = (float)mask[b * 512 + tn];
          }
        }
      }
      __syncthreads();
    }
  }
  // epilogue: s = 512 -> L1 computes t = 511 (r0h/r1f buffer 1)
  if (!isL0) {
    const int t = 511;
    float a0 = b1c, a1 = 0.f, a2 = 0.f, a3 = 0.f;
    const uint2* yp = (const uint2*)&r0h[1][kb];
#pragma unroll
    for (int c = 0; c < 8; ++c) {
      uint2 uu = yp[c * 2 + 0];
      uint2 vv = yp[c * 2 + 1];
      h2 x0 = __builtin_bit_cast(h2, uu.x);
      h2 x1 = __builtin_bit_cast(h2, uu.y);
      h2 x2 = __builtin_bit_cast(h2, vv.x);
      h2 x3 = __builtin_bit_cast(h2, vv.y);
#if __has_builtin(__builtin_amdgcn_fdot2)
      a0 = __builtin_amdgcn_fdot2(Wb2[c * 4 + 0], x0, a0, false);
      a1 = __builtin_amdgcn_fdot2(Wb2[c * 4 + 1], x1, a1, false);
      a2 = __builtin_amdgcn_fdot2(Wb2[c * 4 + 2], x2, a2, false);
      a3 = __builtin_amdgcn_fdot2(Wb2[c * 4 + 3], x3, a3, false);
#else
      a0 += (float)Wb2[c * 4 + 0].x * (float)x0.x +
            (float)Wb2[c * 4 + 0].y * (float)x0.y;
      a1 += (float)Wb2[c * 4 + 1].x * (float)x1.x +
            (float)Wb2[c * 4 + 1].y * (float)x1.y;
      a2 += (float)Wb2[c * 4 + 2].x * (float)x2.x +
            (float)Wb2[c * 4 + 2].y * (float)x2.y;
      a3 += (float)Wb2[c * 4 + 3].x * (float)x3.x +
            (float)Wb2[c * 4 + 3].y * (float)x3.y;
#endif
    }
    const float4* hp = (const float4*)&r1f[1][kb];
#pragma unroll
    for (int c = 0; c < 4; ++c) {
      float4 h0v = hp[c * 4 + 0], h1v = hp[c * 4 + 1];
      float4 h2v = hp[c * 4 + 2], h3v = hp[c * 4 + 3];
      float4 w0 = Wa4[c * 4 + 0], w1 = Wa4[c * 4 + 1];
      float4 w2 = Wa4[c * 4 + 2], w3 = Wa4[c * 4 + 3];
      a0 += w0.x * h0v.x + w0.y * h0v.y + w0.z * h0v.z + w0.w * h0v.w;
      a1 += w1.x * h1v.x + w1.y * h1v.y + w1.z * h1v.z + w1.w * h1v.w;
      a2 += w2.x * h2v.x + w2.y * h2v.y + w2.z * h2v.z + w2.w * h2v.w;
      a3 += w3.x * h3v.x + w3.y * h3v.y + w3.z * h3v.z + w3.w * h3v.w;
    }
    float acc = (a0 + a1) + (a2 + a3);
    acc += __shfl_xor(acc, 1);
    float y = fast_tanh(acc);
    if (half == 1) {
      Y[((size_t)b * 512 + t) * 128 + row] = y * mm[7];
    }
  }
}

// ------------------------- K3 v6: edge RNN, f16 MFMA, 8 waves, 2m x 2n/wave.
// Change vs v5: __launch_bounds__(512,4) to request 2 blocks/CU (VGPR<=128,
// 2x75776B LDS = 151.5K <= 160K) so two blocks' LDS/VALU phases interleave.
#define LDSA 0       // A      [64][64]  f16        :  8192 B
#define LDSN0 8192   // n0     2 x [64][128] f16    : 32768 B
#define LDSN1 40960  // n1     2 x [64][128] f16    : 32768 B
#define LDSPS 73728  // psum   [4][64] f32          :  1024 B
#define LDSTOT 75776

__global__ __launch_bounds__(512, 4) void k3_edge_f16(
    const float* __restrict__ Y, const unsigned short* __restrict__ Wf,
    const float* __restrict__ bih0, const float* __restrict__ bhh0,
    const float* __restrict__ bih1, const float* __restrict__ bhh1,
    const float* __restrict__ clsW, const float* __restrict__ clsb,
    float* __restrict__ adj) {
  extern __shared__ char sm[];
  _Float16* Aq = (_Float16*)(sm + LDSA);
  _Float16* N0 = (_Float16*)(sm + LDSN0);
  _Float16* N1 = (_Float16*)(sm + LDSN1);
  float* psum = (float*)(sm + LDSPS);

  const int tid = threadIdx.x;
  const int w = tid >> 6, l = tid & 63;
  const int mg = w & 1, ng = w >> 1;
  const int colL = l & 15, q = l >> 4;
  const int node0 = blockIdx.x * 64;

  for (int i = tid; i < 2048; i += 512) ((unsigned*)(sm + LDSA))[i] = 0u;
  for (int i = tid; i < 8192; i += 512) ((unsigned*)(sm + LDSN1))[i] = 0u;
  for (int i = tid; i < 8192; i += 512) {
    int nn = i >> 7, k = i & 127;
    float v = Y[(size_t)(node0 + nn) * 128 + k];
    N0[sw(nn, k, 128)] = (_Float16)v;
  }

  f16x8 Wr[2][14];
#pragma unroll
  for (int nt = 0; nt < 2; ++nt)
#pragma unroll
    for (int kc = 0; kc < 14; ++kc)
      Wr[nt][kc] =
          ((const f16x8*)Wf)[(size_t)(((2 * ng + nt) * 14) + kc) * 64 + l];

  float b0v[2], b1v[2], cwv[2];
#pragma unroll
  for (int nt = 0; nt < 2; ++nt) {
    int cg = (2 * ng + nt) * 16 + colL;
    b0v[nt] = bih0[cg] + bhh0[cg];
    b1v[nt] = bih1[cg] + bhh1[cg];
    cwv[nt] = clsW[cg];
  }
  const float cbias = clsb[0];
  const int ipos = (node0 & 511) + l;
  const int mval = min(ipos, 64);
  const int badj = node0 >> 9;

  __syncthreads();

  int p = 0;
  for (int step = 0; step < 64; ++step) {
    _Float16* n0rd = N0 + p * 8192;
    _Float16* n0wr = N0 + (p ^ 1) * 8192;
    _Float16* n1rd = N1 + p * 8192;
    _Float16* n1wr = N1 + (p ^ 1) * 8192;

    f32x4 acc[2][2];
#pragma unroll
    for (int mt = 0; mt < 2; ++mt)
#pragma unroll
      for (int nt = 0; nt < 2; ++nt)
        acc[mt][nt] = (f32x4){b0v[nt], b0v[nt], b0v[nt], b0v[nt]};
#pragma unroll
    for (int kc = 0; kc < 6; ++kc) {
      f16x8 ah[2];
#pragma unroll
      for (int mt = 0; mt < 2; ++mt) {
        int row = mg * 32 + mt * 16 + colL;
        if (kc < 2) {
          int gk = kc * 4 + q;
          ah[mt] = *(const f16x8*)&Aq[row * 64 + ((gk ^ (row & 7)) << 3)];
        } else {
          int gk = (kc - 2) * 4 + q;
          ah[mt] = *(const f16x8*)&n0rd[row * 128 + ((gk ^ (row & 7)) << 3)];
        }
      }
#pragma unroll
      for (int mt = 0; mt < 2; ++mt)
#pragma unroll
        for (int nt = 0; nt < 2; ++nt)
          acc[mt][nt] = MFMAH(ah[mt], Wr[nt][kc], acc[mt][nt]);
    }
#pragma unroll
    for (int mt = 0; mt < 2; ++mt)
#pragma unroll
      for (int nt = 0; nt < 2; ++nt)
#pragma unroll
        for (int rg = 0; rg < 4; ++rg) {
          float v = fast_tanh(acc[mt][nt][rg]);
          int row = mg * 32 + mt * 16 + q * 4 + rg;
          int col = (2 * ng + nt) * 16 + colL;
          n0wr[sw(row, col, 128)] = (_Float16)v;
        }
    __syncthreads();  // bar A: n0 complete

    f32x4 acc2[2][2];
#pragma unroll
    for (int mt = 0; mt < 2; ++mt)
#pragma unroll
      for (int nt = 0; nt < 2; ++nt)
        acc2[mt][nt] = (f32x4){b1v[nt], b1v[nt], b1v[nt], b1v[nt]};
#pragma unroll
    for (int kc = 0; kc < 8; ++kc) {
      const _Float16* src = (kc < 4) ? n0wr : n1rd;
      int gk = (kc & 3) * 4 + q;
      f16x8 ah[2];
#pragma unroll
      for (int mt = 0; mt < 2; ++mt) {
        int row = mg * 32 + mt * 16 + colL;
        ah[mt] = *(const f16x8*)&src[row * 128 + ((gk ^ (row & 7)) << 3)];
      }
#pragma unroll
      for (int mt = 0; mt < 2; ++mt)
#pragma unroll
        for (int nt = 0; nt < 2; ++nt)
          acc2[mt][nt] = MFMAH(ah[mt], Wr[nt][6 + kc], acc2[mt][nt]);
    }
    float pa[2][4];
#pragma unroll
    for (int mt = 0; mt < 2; ++mt)
#pragma unroll
      for (int rg = 0; rg < 4; ++rg) pa[mt][rg] = 0.f;
#pragma unroll
    for (int mt = 0; mt < 2; ++mt)
#pragma unroll
      for (int nt = 0; nt < 2; ++nt)
#pragma unroll
        for (int rg = 0; rg < 4; ++rg) {
          float v = fast_tanh(acc2[mt][nt][rg]);
          pa[mt][rg] += cwv[nt] * v;
          int row = mg * 32 + mt * 16 + q * 4 + rg;
          int col = (2 * ng + nt) * 16 + colL;
          n1wr[sw(row, col, 128)] = (_Float16)v;
        }
#pragma unroll
    for (int mt = 0; mt < 2; ++mt)
#pragma unroll
      for (int rg = 0; rg < 4; ++rg) {
        float s = pa[mt][rg];
        s += __shfl_xor(s, 1);
        s += __shfl_xor(s, 2);
        s += __shfl_xor(s, 4);
        s += __shfl_xor(s, 8);
        pa[mt][rg] = s;
      }
#pragma unroll
    for (int ii = 0; ii < 8; ++ii)
      if (colL == ii) {
        int row = mg * 32 + (ii >> 2) * 16 + q * 4 + (ii & 3);
        psum[ng * 64 + row] = pa[ii >> 2][ii & 3];
      }
    __syncthreads();  // bar B: psum + n1 complete

    {
      float s = cbias + psum[l] + psum[64 + l] + psum[128 + l] +
                psum[192 + l];
      float sg = fast_sigmoid(s);
      if (step < mval)
        Aq[l * 64 + ((((step >> 3) ^ (l & 7)) << 3) | (step & 7))] =
            (_Float16)sg;
    }
    p ^= 1;
  }
  __syncthreads();

  for (int idx = tid; idx < 4096; idx += 512) {
    int nn = idx >> 6, k = idx & 63;
    int nd = node0 + nn;
    int bb = nd >> 9, ii = nd & 511;
    int mm = min(ii, 64);
    if (k < mm) {
      float v = (float)Aq[sw(nn, k, 64)];
      int r = max(0, ii - 64) + k;
      adj[((size_t)bb * 512 + r) * 512 + ii] = v;
    }
  }
}

extern "C" void kernel_launch(void* const* d_in, const int* in_sizes, int n_in,
                              void* d_out, int out_size, void* d_ws,
                              size_t ws_size, hipStream_t stream) {
  const float* x = (const float*)d_in[0];
  const int* mask = (const int*)d_in[1];
  const float* gWih0 = (const float*)d_in[2];
  const float* gWhh0 = (const float*)d_in[3];
  const float* gbih0 = (const float*)d_in[4];
  const float* gbhh0 = (const float*)d_in[5];
  const float* gWih1 = (const float*)d_in[6];
  const float* gWhh1 = (const float*)d_in[7];
  const float* gbih1 = (const float*)d_in[8];
  const float* gbhh1 = (const float*)d_in[9];
  const float* eWih0 = (const float*)d_in[10];
  const float* eWhh0 = (const float*)d_in[11];
  const float* ebih0 = (const float*)d_in[12];
  const float* ebhh0 = (const float*)d_in[13];
  const float* eWih1 = (const float*)d_in[14];
  const float* eWhh1 = (const float*)d_in[15];
  const float* ebih1 = (const float*)d_in[16];
  const float* ebhh1 = (const float*)d_in[17];
  const float* clsW = (const float*)d_in[18];
  const float* clsb = (const float*)d_in[19];
  float* out = (float*)d_out;
  float* Y = out;
  float* adj = out + YSZ;
  float* P0 = adj;  // scratch overlay in adj region; wiped by kzero before k3

  unsigned short* Wf = (unsigned short*)d_ws;
  hipLaunchKernelGGL(k0_prep, dim3(28), dim3(256), 0, stream, eWih0, eWhh0,
                     eWih1, eWhh1, Wf);
  hipLaunchKernelGGL(k1_gemm, dim3(256), dim3(256), 0, stream, x, gWih0,
                     gbih0, gbhh0, P0);
  hipLaunchKernelGGL(k2_v5, dim3(64), dim3(512), 0, stream, P0, gWhh0, gWih1,
                     gWhh1, gbih1, gbhh1, mask, Y);
  hipLaunchKernelGGL(kzero, dim3(2048), dim3(256), 0, stream, (float4*)adj,
                     (int)(ADJSZ / 4));
  hipFuncSetAttribute(reinterpret_cast<const void*>(k3_edge_f16),
                      hipFuncAttributeMaxDynamicSharedMemorySize, LDSTOT);
  hipLaunchKernelGGL(k3_edge_f16, dim3(512), dim3(512), LDSTOT, stream, Y,
                     Wf, ebih0, ebhh0, ebih1, ebhh1, clsW, clsb, adj);
}

// Round 8
// 848.001 us; speedup vs baseline: 1.5406x; 1.5406x over previous
//
#include <hip/hip_runtime.h>

#define B_ 64
#define S_ 512
#define D_ 256
#define H_ 128
#define M_ 64
#define N_ (B_ * S_)                 // 32768 nodes
#define YSZ ((size_t)N_ * H_)        // 4194304 floats
#define ADJSZ ((size_t)B_ * S_ * S_) // 16777216 floats

typedef __attribute__((ext_vector_type(8))) _Float16 f16x8;
typedef __attribute__((ext_vector_type(2))) _Float16 h2;
typedef __attribute__((ext_vector_type(4))) float f32x4;

#define MFMAH(a, b, c) __builtin_amdgcn_mfma_f32_16x16x32_f16(a, b, c, 0, 0, 0)

// weight frag store: 8 n-tiles x 14 k-chunks, 64 lanes x 16B each (f16)
#define WFRAGS (8 * 14)
#define WBYTES ((size_t)WFRAGS * 64 * 16)  // 114688

__device__ __forceinline__ float fast_tanh(float x) {
  float cx = __builtin_amdgcn_fmed3f(x, -10.0f, 10.0f);
  float e = __builtin_amdgcn_exp2f(cx * 2.8853900817779268f);
  float r = __builtin_amdgcn_rcpf(e + 1.0f);
  return fmaf(-2.0f, r, 1.0f);
}
__device__ __forceinline__ float fast_sigmoid(float x) {
  float cx = __builtin_amdgcn_fmed3f(x, -30.0f, 30.0f);
  float e = __builtin_amdgcn_exp2f(cx * -1.4426950408889634f);
  return __builtin_amdgcn_rcpf(1.0f + e);
}

// element index in a [rows][Kc] f16 array, XOR-swizzled 16B (8-elem) granules
__device__ __forceinline__ int sw(int row, int col, int Kc) {
  return row * Kc + ((((col >> 3) ^ (row & 7)) << 3) | (col & 7));
}
// granule-index form for [16][128] state arrays (g = 8-elem granule 0..15)
__device__ __forceinline__ int swu(int row, int g) {
  return row * 128 + (((g ^ (row & 7)) << 3));
}

__device__ __forceinline__ f16x8 pack8(float4 a, float4 b) {
  f16x8 r;
  r[0] = (_Float16)a.x; r[1] = (_Float16)a.y;
  r[2] = (_Float16)a.z; r[3] = (_Float16)a.w;
  r[4] = (_Float16)b.x; r[5] = (_Float16)b.y;
  r[6] = (_Float16)b.z; r[7] = (_Float16)b.w;
  return r;
}

// ---------------------------------------------------------------- zero adj
__global__ void kzero(float4* __restrict__ p, int n4) {
  int i = blockIdx.x * blockDim.x + threadIdx.x;
  int stride = gridDim.x * blockDim.x;
  float4 z = {0.f, 0.f, 0.f, 0.f};
  for (; i < n4; i += stride) p[i] = z;
}

// ---------------- K0: pack f16 weight fragments (native MFMA B-frag order)
__global__ __launch_bounds__(256) void k0_prep(
    const float* __restrict__ eWih0, const float* __restrict__ eWhh0,
    const float* __restrict__ eWih1, const float* __restrict__ eWhh1,
    unsigned short* __restrict__ Wf) {
  int t = blockIdx.x * 256 + threadIdx.x;
  if (t >= WFRAGS * 64) return;
  int fid = t >> 6, lane = t & 63;
  int ntg = fid / 14, kc = fid % 14;
  int j = ntg * 16 + (lane & 15);
  int kbase = (kc < 6 ? kc : kc - 6) * 32 + (lane >> 4) * 8;
  unsigned pk[4];
#pragma unroll
  for (int ii = 0; ii < 4; ++ii) {
    unsigned p2 = 0;
#pragma unroll
    for (int s = 0; s < 2; ++s) {
      int k = kbase + ii * 2 + s;
      float wv;
      if (kc < 6)
        wv = (k < 64) ? eWih0[j * 64 + k] : eWhh0[j * 128 + (k - 64)];
      else
        wv = (k < 128) ? eWih1[j * 128 + k] : eWhh1[j * 128 + (k - 128)];
      _Float16 h = (_Float16)wv;
      unsigned short us = *(unsigned short*)&h;
      p2 |= ((unsigned)us) << (16 * s);
    }
    pk[ii] = p2;
  }
  ((uint4*)Wf)[fid * 64 + lane] = make_uint4(pk[0], pk[1], pk[2], pk[3]);
}

// ------------------------------------------- K1: P0 = x @ Wih0^T + (bih0+bhh0)
__global__ __launch_bounds__(256) void k1_gemm(
    const float* __restrict__ x, const float* __restrict__ W,
    const float* __restrict__ bih, const float* __restrict__ bhh,
    float* __restrict__ P0) {
  __shared__ float Xs[32][132];
  __shared__ float Ws[32][132];
  const int t = threadIdx.x;
  const int ty = t >> 4, tx = t & 15;
  const int n0 = blockIdx.x * 128;
  float acc[8][8];
#pragma unroll
  for (int i = 0; i < 8; ++i)
#pragma unroll
    for (int j = 0; j < 8; ++j) acc[i][j] = 0.f;

  for (int kc = 0; kc < 256; kc += 32) {
    __syncthreads();
#pragma unroll
    for (int l = 0; l < 4; ++l) {
      int idx = t + l * 256;
      int r = idx >> 3, f4 = idx & 7;
      float4 v = *(const float4*)&x[(size_t)(n0 + r) * 256 + kc + f4 * 4];
      Xs[f4 * 4 + 0][r] = v.x; Xs[f4 * 4 + 1][r] = v.y;
      Xs[f4 * 4 + 2][r] = v.z; Xs[f4 * 4 + 3][r] = v.w;
      float4 wv = *(const float4*)&W[(size_t)r * 256 + kc + f4 * 4];
      Ws[f4 * 4 + 0][r] = wv.x; Ws[f4 * 4 + 1][r] = wv.y;
      Ws[f4 * 4 + 2][r] = wv.z; Ws[f4 * 4 + 3][r] = wv.w;
    }
    __syncthreads();
#pragma unroll
    for (int kk = 0; kk < 32; ++kk) {
      float4 xa = *(const float4*)&Xs[kk][ty * 8];
      float4 xb = *(const float4*)&Xs[kk][ty * 8 + 4];
      float4 wa = *(const float4*)&Ws[kk][tx * 8];
      float4 wb = *(const float4*)&Ws[kk][tx * 8 + 4];
      float xr[8] = {xa.x, xa.y, xa.z, xa.w, xb.x, xb.y, xb.z, xb.w};
      float wr[8] = {wa.x, wa.y, wa.z, wa.w, wb.x, wb.y, wb.z, wb.w};
#pragma unroll
      for (int i = 0; i < 8; ++i)
#pragma unroll
        for (int j = 0; j < 8; ++j) acc[i][j] += xr[i] * wr[j];
    }
  }
  float bias[8];
#pragma unroll
  for (int j = 0; j < 8; ++j) bias[j] = bih[tx * 8 + j] + bhh[tx * 8 + j];
#pragma unroll
  for (int i = 0; i < 8; ++i) {
    float4 s0 = make_float4(acc[i][0] + bias[0], acc[i][1] + bias[1],
                            acc[i][2] + bias[2], acc[i][3] + bias[3]);
    float4 s1 = make_float4(acc[i][4] + bias[4], acc[i][5] + bias[5],
                            acc[i][6] + bias[6], acc[i][7] + bias[7]);
    size_t base = (size_t)(n0 + ty * 8 + i) * 128 + tx * 8;
    *(float4*)&P0[base] = s0;
    *(float4*)&P0[base + 4] = s1;
  }
}

// ------------------------- K2 v6: graph RNN as batched MFMA over batch dim.
// 4 blocks x 16 batch rows. 4 waves: w0,w1 = layer0 (M-tiles 0-3/4-7),
// w2,w3 = layer1, software-pipelined (L1 lags L0 by one step; both only need
// h0(s-1)). A = weight tile (VGPR-resident frags), B = f16 state [K][16 brow]
// from swizzled LDS, D[n_out][brow]. 1 barrier/superstep.
#define K2STEP(S, PP)                                                         \
  {                                                                           \
    if (isL0 && (S) < 512) {                                                  \
      const int rd0 = ((S)&1) ^ 1;                                            \
      f32x4 acc[4];                                                           \
      _Pragma("unroll") for (int i = 0; i < 4; ++i)                           \
          acc[i] = __builtin_bit_cast(f32x4, PP[i]);                          \
      _Pragma("unroll") for (int kc = 0; kc < 4; ++kc) {                      \
        f16x8 bf = *(const f16x8*)&h0s[rd0][swu(colB, kc * 4 + q)];           \
        _Pragma("unroll") for (int i = 0; i < 4; ++i)                         \
            acc[i] = MFMAH(WA[i][kc], bf, acc[i]);                            \
      }                                                                       \
      int tn = ((S) + 2 < 512) ? (S) + 2 : 511;                               \
      _Pragma("unroll") for (int i = 0; i < 4; ++i)                           \
          PP[i] = *(const float4*)(p0base[i] + (size_t)tn * 128);             \
      _Pragma("unroll") for (int i = 0; i < 4; ++i) {                         \
        float v0 = fast_tanh(acc[i][0]), v1 = fast_tanh(acc[i][1]);           \
        float v2 = fast_tanh(acc[i][2]), v3 = fast_tanh(acc[i][3]);           \
        int nb = (wl * 4 + i) * 16 + q * 4;                                   \
        int g = nb >> 3;                                                      \
        int idx = colB * 128 + (((g ^ (colB & 7)) << 3) | (nb & 7));          \
        h2 lo = {(_Float16)v0, (_Float16)v1};                                 \
        h2 hi = {(_Float16)v2, (_Float16)v3};                                 \
        uint2 u = {__builtin_bit_cast(unsigned, lo),                          \
                   __builtin_bit_cast(unsigned, hi)};                         \
        *(uint2*)&h0s[(S)&1][idx] = u;                                        \
      }                                                                       \
    } else if (!isL0 && (S) >= 1) {                                           \
      const int t = (S)-1;                                                    \
      const int rb = t & 1;                                                   \
      f32x4 acc[4];                                                           \
      _Pragma("unroll") for (int i = 0; i < 4; ++i) acc[i] = b1v[i];          \
      _Pragma("unroll") for (int kc = 0; kc < 4; ++kc) {                      \
        f16x8 bf = *(const f16x8*)&h0s[rb][swu(colB, kc * 4 + q)];            \
        _Pragma("unroll") for (int i = 0; i < 4; ++i)                         \
            acc[i] = MFMAH(WA[i][kc], bf, acc[i]);                            \
      }                                                                       \
      _Pragma("unroll") for (int kc = 0; kc < 4; ++kc) {                      \
        f16x8 bf = *(const f16x8*)&h1s[rb ^ 1][swu(colB, kc * 4 + q)];        \
        _Pragma("unroll") for (int i = 0; i < 4; ++i)                         \
            acc[i] = MFMAH(WB[i][kc], bf, acc[i]);                            \
      }                                                                       \
      float m = mk[colB][t];                                                  \
      _Pragma("unroll") for (int i = 0; i < 4; ++i) {                         \
        float v0 = fast_tanh(acc[i][0]), v1 = fast_tanh(acc[i][1]);           \
        float v2 = fast_tanh(acc[i][2]), v3 = fast_tanh(acc[i][3]);           \
        int nb = (wl * 4 + i) * 16 + q * 4;                                   \
        int g = nb >> 3;                                                      \
        int idx = colB * 128 + (((g ^ (colB & 7)) << 3) | (nb & 7));          \
        h2 lo = {(_Float16)v0, (_Float16)v1};                                 \
        h2 hi = {(_Float16)v2, (_Float16)v3};                                 \
        uint2 u = {__builtin_bit_cast(unsigned, lo),                          \
                   __builtin_bit_cast(unsigned, hi)};                         \
        *(uint2*)&h1s[rb][idx] = u;                                           \
        float4 yv = {v0 * m, v1 * m, v2 * m, v3 * m};                         \
        *(float4*)&Y[((size_t)(b0 + colB) * 512 + t) * 128 + nb] = yv;        \
      }                                                                       \
    }                                                                         \
    __syncthreads();                                                          \
  }

__global__ __launch_bounds__(256, 1) void k2_v6(
    const float* __restrict__ P0, const float* __restrict__ Whh0,
    const float* __restrict__ Wih1, const float* __restrict__ Whh1,
    const float* __restrict__ bih1, const float* __restrict__ bhh1,
    const int* __restrict__ mask, float* __restrict__ Y) {
  __shared__ _Float16 h0s[2][16 * 128];
  __shared__ _Float16 h1s[2][16 * 128];
  __shared__ float mk[16][516];  // padded: stride 516 breaks bank aliasing
  const int tid = threadIdx.x;
  const int w = tid >> 6, l = tid & 63;
  const int b0 = blockIdx.x * 16;
  const int colB = l & 15;  // batch row within block (B col / D col)
  const int q = l >> 4;
  const bool isL0 = (w < 2);
  const int wl = isL0 ? w : (w - 2);

  // stage mask -> LDS as float
  for (int i = tid; i < 16 * 512; i += 256) {
    int bb = i >> 9, t = i & 511;
    mk[bb][t] = (float)mask[(b0 + bb) * 512 + t];
  }
  // zero read-before-write state buffers (h0s[1], h1s[1])
  for (int i = tid; i < 1024; i += 256) {
    ((unsigned*)&h0s[1][0])[i] = 0u;
    ((unsigned*)&h1s[1][0])[i] = 0u;
  }

  // resident weight A-fragments: lane l holds rows m=(tile*16+(l&15)),
  // k = kc*32 + (l>>4)*8 + 0..7
  f16x8 WA[4][4];  // L0: Whh0 ; L1: Wih1
  f16x8 WB[4][4];  // L1 only: Whh1
  {
    const float* src = isL0 ? Whh0 : Wih1;
#pragma unroll
    for (int i = 0; i < 4; ++i)
#pragma unroll
      for (int kc = 0; kc < 4; ++kc) {
        const float* r =
            src + ((wl * 4 + i) * 16 + colB) * 128 + kc * 32 + q * 8;
        WA[i][kc] = pack8(*(const float4*)r, *(const float4*)(r + 4));
      }
    if (!isL0) {
#pragma unroll
      for (int i = 0; i < 4; ++i)
#pragma unroll
        for (int kc = 0; kc < 4; ++kc) {
          const float* r =
              Whh1 + ((wl * 4 + i) * 16 + colB) * 128 + kc * 32 + q * 8;
          WB[i][kc] = pack8(*(const float4*)r, *(const float4*)(r + 4));
        }
    }
  }
  // layer-1 bias in D layout; P0 base pointers (L0)
  f32x4 b1v[4];
  const float* p0base[4];
#pragma unroll
  for (int i = 0; i < 4; ++i) {
    int nb = (wl * 4 + i) * 16 + q * 4;
    if (!isL0) {
      b1v[i] = (f32x4){bih1[nb] + bhh1[nb], bih1[nb + 1] + bhh1[nb + 1],
                       bih1[nb + 2] + bhh1[nb + 2], bih1[nb + 3] + bhh1[nb + 3]};
    } else {
      b1v[i] = (f32x4){0.f, 0.f, 0.f, 0.f};
    }
    p0base[i] = P0 + (size_t)(b0 + colB) * 512 * 128 + nb;
  }
  // P0 prefetch (depth 2, ping-pong)
  float4 pp0[4], pp1[4];
  if (isL0) {
#pragma unroll
    for (int i = 0; i < 4; ++i) {
      pp0[i] = *(const float4*)(p0base[i]);
      pp1[i] = *(const float4*)(p0base[i] + 128);
    }
  }
  __syncthreads();

  for (int s2 = 0; s2 < 512; s2 += 2) {
    K2STEP(s2, pp0);
    K2STEP(s2 + 1, pp1);
  }
  K2STEP(512, pp0);  // epilogue: L1 computes t=511 (L0 branch guarded off)
}

// ------------------------- K3 v5 (reverted): edge RNN, f16 MFMA, 8 waves,
// 2m x 2n per wave, __launch_bounds__(512,2). (512,4) in R7 forced VGPR=64 ->
// weight frags spilled to scratch, FETCH 8.7MB -> 2.6GB, 478 -> 881us.
#define LDSA 0       // A      [64][64]  f16        :  8192 B
#define LDSN0 8192   // n0     2 x [64][128] f16    : 32768 B
#define LDSN1 40960  // n1     2 x [64][128] f16    : 32768 B
#define LDSPS 73728  // psum   [4][64] f32          :  1024 B
#define LDSTOT 75776

__global__ __launch_bounds__(512, 2) void k3_edge_f16(
    const float* __restrict__ Y, const unsigned short* __restrict__ Wf,
    const float* __restrict__ bih0, const float* __restrict__ bhh0,
    const float* __restrict__ bih1, const float* __restrict__ bhh1,
    const float* __restrict__ clsW, const float* __restrict__ clsb,
    float* __restrict__ adj) {
  extern __shared__ char sm[];
  _Float16* Aq = (_Float16*)(sm + LDSA);
  _Float16* N0 = (_Float16*)(sm + LDSN0);
  _Float16* N1 = (_Float16*)(sm + LDSN1);
  float* psum = (float*)(sm + LDSPS);

  const int tid = threadIdx.x;
  const int w = tid >> 6, l = tid & 63;
  const int mg = w & 1, ng = w >> 1;
  const int colL = l & 15, q = l >> 4;
  const int node0 = blockIdx.x * 64;

  for (int i = tid; i < 2048; i += 512) ((unsigned*)(sm + LDSA))[i] = 0u;
  for (int i = tid; i < 8192; i += 512) ((unsigned*)(sm + LDSN1))[i] = 0u;
  for (int i = tid; i < 8192; i += 512) {
    int nn = i >> 7, k = i & 127;
    float v = Y[(size_t)(node0 + nn) * 128 + k];
    N0[sw(nn, k, 128)] = (_Float16)v;
  }

  f16x8 Wr[2][14];
#pragma unroll
  for (int nt = 0; nt < 2; ++nt)
#pragma unroll
    for (int kc = 0; kc < 14; ++kc)
      Wr[nt][kc] =
          ((const f16x8*)Wf)[(size_t)(((2 * ng + nt) * 14) + kc) * 64 + l];

  float b0v[2], b1v[2], cwv[2];
#pragma unroll
  for (int nt = 0; nt < 2; ++nt) {
    int cg = (2 * ng + nt) * 16 + colL;
    b0v[nt] = bih0[cg] + bhh0[cg];
    b1v[nt] = bih1[cg] + bhh1[cg];
    cwv[nt] = clsW[cg];
  }
  const float cbias = clsb[0];
  const int ipos = (node0 & 511) + l;
  const int mval = min(ipos, 64);
  const int badj = node0 >> 9;

  __syncthreads();

  int p = 0;
  for (int step = 0; step < 64; ++step) {
    _Float16* n0rd = N0 + p * 8192;
    _Float16* n0wr = N0 + (p ^ 1) * 8192;
    _Float16* n1rd = N1 + p * 8192;
    _Float16* n1wr = N1 + (p ^ 1) * 8192;

    f32x4 acc[2][2];
#pragma unroll
    for (int mt = 0; mt < 2; ++mt)
#pragma unroll
      for (int nt = 0; nt < 2; ++nt)
        acc[mt][nt] = (f32x4){b0v[nt], b0v[nt], b0v[nt], b0v[nt]};
#pragma unroll
    for (int kc = 0; kc < 6; ++kc) {
      f16x8 ah[2];
#pragma unroll
      for (int mt = 0; mt < 2; ++mt) {
        int row = mg * 32 + mt * 16 + colL;
        if (kc < 2) {
          int gk = kc * 4 + q;
          ah[mt] = *(const f16x8*)&Aq[row * 64 + ((gk ^ (row & 7)) << 3)];
        } else {
          int gk = (kc - 2) * 4 + q;
          ah[mt] = *(const f16x8*)&n0rd[row * 128 + ((gk ^ (row & 7)) << 3)];
        }
      }
#pragma unroll
      for (int mt = 0; mt < 2; ++mt)
#pragma unroll
        for (int nt = 0; nt < 2; ++nt)
          acc[mt][nt] = MFMAH(ah[mt], Wr[nt][kc], acc[mt][nt]);
    }
#pragma unroll
    for (int mt = 0; mt < 2; ++mt)
#pragma unroll
      for (int nt = 0; nt < 2; ++nt)
#pragma unroll
        for (int rg = 0; rg < 4; ++rg) {
          float v = fast_tanh(acc[mt][nt][rg]);
          int row = mg * 32 + mt * 16 + q * 4 + rg;
          int col = (2 * ng + nt) * 16 + colL;
          n0wr[sw(row, col, 128)] = (_Float16)v;
        }
    __syncthreads();  // bar A: n0 complete

    f32x4 acc2[2][2];
#pragma unroll
    for (int mt = 0; mt < 2; ++mt)
#pragma unroll
      for (int nt = 0; nt < 2; ++nt)
        acc2[mt][nt] = (f32x4){b1v[nt], b1v[nt], b1v[nt], b1v[nt]};
#pragma unroll
    for (int kc = 0; kc < 8; ++kc) {
      const _Float16* src = (kc < 4) ? n0wr : n1rd;
      int gk = (kc & 3) * 4 + q;
      f16x8 ah[2];
#pragma unroll
      for (int mt = 0; mt < 2; ++mt) {
        int row = mg * 32 + mt * 16 + colL;
        ah[mt] = *(const f16x8*)&src[row * 128 + ((gk ^ (row & 7)) << 3)];
      }
#pragma unroll
      for (int mt = 0; mt < 2; ++mt)
#pragma unroll
        for (int nt = 0; nt < 2; ++nt)
          acc2[mt][nt] = MFMAH(ah[mt], Wr[nt][6 + kc], acc2[mt][nt]);
    }
    float pa[2][4];
#pragma unroll
    for (int mt = 0; mt < 2; ++mt)
#pragma unroll
      for (int rg = 0; rg < 4; ++rg) pa[mt][rg] = 0.f;
#pragma unroll
    for (int mt = 0; mt < 2; ++mt)
#pragma unroll
      for (int nt = 0; nt < 2; ++nt)
#pragma unroll
        for (int rg = 0; rg < 4; ++rg) {
          float v = fast_tanh(acc2[mt][nt][rg]);
          pa[mt][rg] += cwv[nt] * v;
          int row = mg * 32 + mt * 16 + q * 4 + rg;
          int col = (2 * ng + nt) * 16 + colL;
          n1wr[sw(row, col, 128)] = (_Float16)v;
        }
#pragma unroll
    for (int mt = 0; mt < 2; ++mt)
#pragma unroll
      for (int rg = 0; rg < 4; ++rg) {
        float s = pa[mt][rg];
        s += __shfl_xor(s, 1);
        s += __shfl_xor(s, 2);
        s += __shfl_xor(s, 4);
        s += __shfl_xor(s, 8);
        pa[mt][rg] = s;
      }
#pragma unroll
    for (int ii = 0; ii < 8; ++ii)
      if (colL == ii) {
        int row = mg * 32 + (ii >> 2) * 16 + q * 4 + (ii & 3);
        psum[ng * 64 + row] = pa[ii >> 2][ii & 3];
      }
    __syncthreads();  // bar B: psum + n1 complete

    {
      float s = cbias + psum[l] + psum[64 + l] + psum[128 + l] +
                psum[192 + l];
      float sg = fast_sigmoid(s);
      if (step < mval)
        Aq[l * 64 + ((((step >> 3) ^ (l & 7)) << 3) | (step & 7))] =
            (_Float16)sg;
    }
    p ^= 1;
  }
  __syncthreads();

  for (int idx = tid; idx < 4096; idx += 512) {
    int nn = idx >> 6, k = idx & 63;
    int nd = node0 + nn;
    int bb = nd >> 9, ii = nd & 511;
    int mm = min(ii, 64);
    if (k < mm) {
      float v = (float)Aq[sw(nn, k, 64)];
      int r = max(0, ii - 64) + k;
      adj[((size_t)bb * 512 + r) * 512 + ii] = v;
    }
  }
}

extern "C" void kernel_launch(void* const* d_in, const int* in_sizes, int n_in,
                              void* d_out, int out_size, void* d_ws,
                              size_t ws_size, hipStream_t stream) {
  const float* x = (const float*)d_in[0];
  const int* mask = (const int*)d_in[1];
  const float* gWih0 = (const float*)d_in[2];
  const float* gWhh0 = (const float*)d_in[3];
  const float* gbih0 = (const float*)d_in[4];
  const float* gbhh0 = (const float*)d_in[5];
  const float* gWih1 = (const float*)d_in[6];
  const float* gWhh1 = (const float*)d_in[7];
  const float* gbih1 = (const float*)d_in[8];
  const float* gbhh1 = (const float*)d_in[9];
  const float* eWih0 = (const float*)d_in[10];
  const float* eWhh0 = (const float*)d_in[11];
  const float* ebih0 = (const float*)d_in[12];
  const float* ebhh0 = (const float*)d_in[13];
  const float* eWih1 = (const float*)d_in[14];
  const float* eWhh1 = (const float*)d_in[15];
  const float* ebih1 = (const float*)d_in[16];
  const float* ebhh1 = (const float*)d_in[17];
  const float* clsW = (const float*)d_in[18];
  const float* clsb = (const float*)d_in[19];
  float* out = (float*)d_out;
  float* Y = out;
  float* adj = out + YSZ;
  float* P0 = adj;  // scratch overlay in adj region; wiped by kzero before k3

  unsigned short* Wf = (unsigned short*)d_ws;
  hipLaunchKernelGGL(k0_prep, dim3(28), dim3(256), 0, stream, eWih0, eWhh0,
                     eWih1, eWhh1, Wf);
  hipLaunchKernelGGL(k1_gemm, dim3(256), dim3(256), 0, stream, x, gWih0,
                     gbih0, gbhh0, P0);
  hipLaunchKernelGGL(k2_v6, dim3(4), dim3(256), 0, stream, P0, gWhh0, gWih1,
                     gWhh1, gbih1, gbhh1, mask, Y);
  hipLaunchKernelGGL(kzero, dim3(2048), dim3(256), 0, stream, (float4*)adj,
                     (int)(ADJSZ / 4));
  hipFuncSetAttribute(reinterpret_cast<const void*>(k3_edge_f16),
                      hipFuncAttributeMaxDynamicSharedMemorySize, LDSTOT);
  hipLaunchKernelGGL(k3_edge_f16, dim3(512), dim3(512), LDSTOT, stream, Y,
                     Wf, ebih0, ebhh0, ebih1, ebhh1, clsW, clsb, adj);
}

// Round 9
// 748.236 us; speedup vs baseline: 1.7461x; 1.1333x over previous
//
#include <hip/hip_runtime.h>

#define B_ 64
#define S_ 512
#define D_ 256
#define H_ 128
#define M_ 64
#define N_ (B_ * S_)                 // 32768 nodes
#define YSZ ((size_t)N_ * H_)        // 4194304 floats
#define ADJSZ ((size_t)B_ * S_ * S_) // 16777216 floats

typedef __attribute__((ext_vector_type(8))) _Float16 f16x8;
typedef __attribute__((ext_vector_type(2))) _Float16 h2;
typedef __attribute__((ext_vector_type(4))) float f32x4;

#define MFMAH(a, b, c) __builtin_amdgcn_mfma_f32_16x16x32_f16(a, b, c, 0, 0, 0)

// weight frag store: 8 n-tiles x 14 k-chunks, 64 lanes x 16B each (f16)
#define WFRAGS (8 * 14)
#define WBYTES ((size_t)WFRAGS * 64 * 16)  // 114688

__device__ __forceinline__ float fast_tanh(float x) {
  float cx = __builtin_amdgcn_fmed3f(x, -10.0f, 10.0f);
  float e = __builtin_amdgcn_exp2f(cx * 2.8853900817779268f);
  float r = __builtin_amdgcn_rcpf(e + 1.0f);
  return fmaf(-2.0f, r, 1.0f);
}
__device__ __forceinline__ float fast_sigmoid(float x) {
  float cx = __builtin_amdgcn_fmed3f(x, -30.0f, 30.0f);
  float e = __builtin_amdgcn_exp2f(cx * -1.4426950408889634f);
  return __builtin_amdgcn_rcpf(1.0f + e);
}

// element index in a [rows][Kc] f16 array, XOR-swizzled 16B (8-elem) granules
__device__ __forceinline__ int sw(int row, int col, int Kc) {
  return row * Kc + ((((col >> 3) ^ (row & 7)) << 3) | (col & 7));
}
// granule-index form for [16][128] state arrays (g = 8-elem granule 0..15)
__device__ __forceinline__ int swu(int row, int g) {
  return row * 128 + (((g ^ (row & 7)) << 3));
}

__device__ __forceinline__ f16x8 pack8(float4 a, float4 b) {
  f16x8 r;
  r[0] = (_Float16)a.x; r[1] = (_Float16)a.y;
  r[2] = (_Float16)a.z; r[3] = (_Float16)a.w;
  r[4] = (_Float16)b.x; r[5] = (_Float16)b.y;
  r[6] = (_Float16)b.z; r[7] = (_Float16)b.w;
  return r;
}

// ---------------- K0: pack f16 weight fragments (native MFMA B-frag order)
__global__ __launch_bounds__(256) void k0_prep(
    const float* __restrict__ eWih0, const float* __restrict__ eWhh0,
    const float* __restrict__ eWih1, const float* __restrict__ eWhh1,
    unsigned short* __restrict__ Wf) {
  int t = blockIdx.x * 256 + threadIdx.x;
  if (t >= WFRAGS * 64) return;
  int fid = t >> 6, lane = t & 63;
  int ntg = fid / 14, kc = fid % 14;
  int j = ntg * 16 + (lane & 15);
  int kbase = (kc < 6 ? kc : kc - 6) * 32 + (lane >> 4) * 8;
  unsigned pk[4];
#pragma unroll
  for (int ii = 0; ii < 4; ++ii) {
    unsigned p2 = 0;
#pragma unroll
    for (int s = 0; s < 2; ++s) {
      int k = kbase + ii * 2 + s;
      float wv;
      if (kc < 6)
        wv = (k < 64) ? eWih0[j * 64 + k] : eWhh0[j * 128 + (k - 64)];
      else
        wv = (k < 128) ? eWih1[j * 128 + k] : eWhh1[j * 128 + (k - 128)];
      _Float16 h = (_Float16)wv;
      unsigned short us = *(unsigned short*)&h;
      p2 |= ((unsigned)us) << (16 * s);
    }
    pk[ii] = p2;
  }
  ((uint4*)Wf)[fid * 64 + lane] = make_uint4(pk[0], pk[1], pk[2], pk[3]);
}

// ------------------------------------------- K1: P0 = x @ Wih0^T + (bih0+bhh0)
__global__ __launch_bounds__(256) void k1_gemm(
    const float* __restrict__ x, const float* __restrict__ W,
    const float* __restrict__ bih, const float* __restrict__ bhh,
    float* __restrict__ P0) {
  __shared__ float Xs[32][132];
  __shared__ float Ws[32][132];
  const int t = threadIdx.x;
  const int ty = t >> 4, tx = t & 15;
  const int n0 = blockIdx.x * 128;
  float acc[8][8];
#pragma unroll
  for (int i = 0; i < 8; ++i)
#pragma unroll
    for (int j = 0; j < 8; ++j) acc[i][j] = 0.f;

  for (int kc = 0; kc < 256; kc += 32) {
    __syncthreads();
#pragma unroll
    for (int l = 0; l < 4; ++l) {
      int idx = t + l * 256;
      int r = idx >> 3, f4 = idx & 7;
      float4 v = *(const float4*)&x[(size_t)(n0 + r) * 256 + kc + f4 * 4];
      Xs[f4 * 4 + 0][r] = v.x; Xs[f4 * 4 + 1][r] = v.y;
      Xs[f4 * 4 + 2][r] = v.z; Xs[f4 * 4 + 3][r] = v.w;
      float4 wv = *(const float4*)&W[(size_t)r * 256 + kc + f4 * 4];
      Ws[f4 * 4 + 0][r] = wv.x; Ws[f4 * 4 + 1][r] = wv.y;
      Ws[f4 * 4 + 2][r] = wv.z; Ws[f4 * 4 + 3][r] = wv.w;
    }
    __syncthreads();
#pragma unroll
    for (int kk = 0; kk < 32; ++kk) {
      float4 xa = *(const float4*)&Xs[kk][ty * 8];
      float4 xb = *(const float4*)&Xs[kk][ty * 8 + 4];
      float4 wa = *(const float4*)&Ws[kk][tx * 8];
      float4 wb = *(const float4*)&Ws[kk][tx * 8 + 4];
      float xr[8] = {xa.x, xa.y, xa.z, xa.w, xb.x, xb.y, xb.z, xb.w};
      float wr[8] = {wa.x, wa.y, wa.z, wa.w, wb.x, wb.y, wb.z, wb.w};
#pragma unroll
      for (int i = 0; i < 8; ++i)
#pragma unroll
        for (int j = 0; j < 8; ++j) acc[i][j] += xr[i] * wr[j];
    }
  }
  float bias[8];
#pragma unroll
  for (int j = 0; j < 8; ++j) bias[j] = bih[tx * 8 + j] + bhh[tx * 8 + j];
#pragma unroll
  for (int i = 0; i < 8; ++i) {
    float4 s0 = make_float4(acc[i][0] + bias[0], acc[i][1] + bias[1],
                            acc[i][2] + bias[2], acc[i][3] + bias[3]);
    float4 s1 = make_float4(acc[i][4] + bias[4], acc[i][5] + bias[5],
                            acc[i][6] + bias[6], acc[i][7] + bias[7]);
    size_t base = (size_t)(n0 + ty * 8 + i) * 128 + tx * 8;
    *(float4*)&P0[base] = s0;
    *(float4*)&P0[base + 4] = s1;
  }
}

// ------------------------- K2 v7: batched-MFMA graph RNN, 8 waves (512 thr).
// Waves 0-3 = layer0 (2 m-tiles each), 4-7 = layer1 (pipelined, lags 1 step).
// 2 waves/SIMD for latency overlap; per-wave MFMA chains halved vs v6 (which
// ran 1 wave/SIMD -> fully exposed ~1450cyc/step latency chain).
#define K2STEP(S, PP)                                                         \
  {                                                                           \
    if (isL0 && (S) < 512) {                                                  \
      const int rd0 = ((S)&1) ^ 1;                                            \
      f32x4 acc[2];                                                           \
      _Pragma("unroll") for (int i = 0; i < 2; ++i)                           \
          acc[i] = __builtin_bit_cast(f32x4, PP[i]);                          \
      _Pragma("unroll") for (int kc = 0; kc < 4; ++kc) {                      \
        f16x8 bf = *(const f16x8*)&h0s[rd0][swu(colB, kc * 4 + q)];           \
        _Pragma("unroll") for (int i = 0; i < 2; ++i)                         \
            acc[i] = MFMAH(WA[i][kc], bf, acc[i]);                            \
      }                                                                       \
      int tn = ((S) + 2 < 512) ? (S) + 2 : 511;                               \
      _Pragma("unroll") for (int i = 0; i < 2; ++i)                           \
          PP[i] = *(const float4*)(p0base[i] + (size_t)tn * 128);             \
      _Pragma("unroll") for (int i = 0; i < 2; ++i) {                         \
        float v0 = fast_tanh(acc[i][0]), v1 = fast_tanh(acc[i][1]);           \
        float v2 = fast_tanh(acc[i][2]), v3 = fast_tanh(acc[i][3]);           \
        int nb = (wl * 2 + i) * 16 + q * 4;                                   \
        int g = nb >> 3;                                                      \
        int idx = colB * 128 + (((g ^ (colB & 7)) << 3) | (nb & 7));          \
        h2 lo = {(_Float16)v0, (_Float16)v1};                                 \
        h2 hi = {(_Float16)v2, (_Float16)v3};                                 \
        uint2 u = {__builtin_bit_cast(unsigned, lo),                          \
                   __builtin_bit_cast(unsigned, hi)};                         \
        *(uint2*)&h0s[(S)&1][idx] = u;                                        \
      }                                                                       \
    } else if (!isL0 && (S) >= 1) {                                           \
      const int t = (S)-1;                                                    \
      const int rb = t & 1;                                                   \
      f32x4 acc[2];                                                           \
      _Pragma("unroll") for (int i = 0; i < 2; ++i) acc[i] = b1v[i];          \
      _Pragma("unroll") for (int kc = 0; kc < 4; ++kc) {                      \
        f16x8 bf = *(const f16x8*)&h0s[rb][swu(colB, kc * 4 + q)];            \
        _Pragma("unroll") for (int i = 0; i < 2; ++i)                         \
            acc[i] = MFMAH(WA[i][kc], bf, acc[i]);                            \
      }                                                                       \
      _Pragma("unroll") for (int kc = 0; kc < 4; ++kc) {                      \
        f16x8 bf = *(const f16x8*)&h1s[rb ^ 1][swu(colB, kc * 4 + q)];        \
        _Pragma("unroll") for (int i = 0; i < 2; ++i)                         \
            acc[i] = MFMAH(WB[i][kc], bf, acc[i]);                            \
      }                                                                       \
      float m = mk[colB][t];                                                  \
      _Pragma("unroll") for (int i = 0; i < 2; ++i) {                         \
        float v0 = fast_tanh(acc[i][0]), v1 = fast_tanh(acc[i][1]);           \
        float v2 = fast_tanh(acc[i][2]), v3 = fast_tanh(acc[i][3]);           \
        int nb = (wl * 2 + i) * 16 + q * 4;                                   \
        int g = nb >> 3;                                                      \
        int idx = colB * 128 + (((g ^ (colB & 7)) << 3) | (nb & 7));          \
        h2 lo = {(_Float16)v0, (_Float16)v1};                                 \
        h2 hi = {(_Float16)v2, (_Float16)v3};                                 \
        uint2 u = {__builtin_bit_cast(unsigned, lo),                          \
                   __builtin_bit_cast(unsigned, hi)};                         \
        *(uint2*)&h1s[rb][idx] = u;                                           \
        float4 yv = {v0 * m, v1 * m, v2 * m, v3 * m};                         \
        *(float4*)&Y[((size_t)(b0 + colB) * 512 + t) * 128 + nb] = yv;        \
      }                                                                       \
    }                                                                         \
    __syncthreads();                                                          \
  }

__global__ __launch_bounds__(512, 1) void k2_v7(
    const float* __restrict__ P0, const float* __restrict__ Whh0,
    const float* __restrict__ Wih1, const float* __restrict__ Whh1,
    const float* __restrict__ bih1, const float* __restrict__ bhh1,
    const int* __restrict__ mask, float* __restrict__ Y) {
  __shared__ _Float16 h0s[2][16 * 128];
  __shared__ _Float16 h1s[2][16 * 128];
  __shared__ float mk[16][516];  // padded stride
  const int tid = threadIdx.x;
  const int w = tid >> 6, l = tid & 63;
  const int b0 = blockIdx.x * 16;
  const int colB = l & 15;  // batch row within block
  const int q = l >> 4;
  const bool isL0 = (w < 4);
  const int wl = isL0 ? w : (w - 4);

  // stage mask -> LDS as float
  for (int i = tid; i < 16 * 512; i += 512) {
    int bb = i >> 9, t = i & 511;
    mk[bb][t] = (float)mask[(b0 + bb) * 512 + t];
  }
  // zero read-before-write state buffers (h0s[1], h1s[1])
  for (int i = tid; i < 1024; i += 512) {
    ((unsigned*)&h0s[1][0])[i] = 0u;
    ((unsigned*)&h1s[1][0])[i] = 0u;
  }

  // resident weight A-fragments: lane holds rows m=(tile*16+(l&15)),
  // k = kc*32 + (l>>4)*8 + 0..7
  f16x8 WA[2][4];  // L0: Whh0 ; L1: Wih1
  f16x8 WB[2][4];  // L1 only: Whh1
  {
    const float* src = isL0 ? Whh0 : Wih1;
#pragma unroll
    for (int i = 0; i < 2; ++i)
#pragma unroll
      for (int kc = 0; kc < 4; ++kc) {
        const float* r =
            src + ((wl * 2 + i) * 16 + colB) * 128 + kc * 32 + q * 8;
        WA[i][kc] = pack8(*(const float4*)r, *(const float4*)(r + 4));
      }
    if (!isL0) {
#pragma unroll
      for (int i = 0; i < 2; ++i)
#pragma unroll
        for (int kc = 0; kc < 4; ++kc) {
          const float* r =
              Whh1 + ((wl * 2 + i) * 16 + colB) * 128 + kc * 32 + q * 8;
          WB[i][kc] = pack8(*(const float4*)r, *(const float4*)(r + 4));
        }
    }
  }
  f32x4 b1v[2];
  const float* p0base[2];
#pragma unroll
  for (int i = 0; i < 2; ++i) {
    int nb = (wl * 2 + i) * 16 + q * 4;
    if (!isL0) {
      b1v[i] = (f32x4){bih1[nb] + bhh1[nb], bih1[nb + 1] + bhh1[nb + 1],
                       bih1[nb + 2] + bhh1[nb + 2], bih1[nb + 3] + bhh1[nb + 3]};
    } else {
      b1v[i] = (f32x4){0.f, 0.f, 0.f, 0.f};
    }
    p0base[i] = P0 + (size_t)(b0 + colB) * 512 * 128 + nb;
  }
  float4 pp0[2], pp1[2];
  if (isL0) {
#pragma unroll
    for (int i = 0; i < 2; ++i) {
      pp0[i] = *(const float4*)(p0base[i]);
      pp1[i] = *(const float4*)(p0base[i] + 128);
    }
  }
  __syncthreads();

  for (int s2 = 0; s2 < 512; s2 += 2) {
    K2STEP(s2, pp0);
    K2STEP(s2 + 1, pp1);
  }
  K2STEP(512, pp0);  // epilogue: L1 computes t=511
}

// ------------------------- K3 v7: edge RNN, f16 MFMA, 8 waves, 2m x 2n/wave
// (core loop = proven v5). Epilogue now writes the FULL 512x64 adj column
// tile (zeros + band) -> kzero kernel eliminated, adj written exactly once.
#define LDSA 0       // A      [64][64]  f16        :  8192 B
#define LDSN0 8192   // n0     2 x [64][128] f16    : 32768 B
#define LDSN1 40960  // n1     2 x [64][128] f16    : 32768 B
#define LDSPS 73728  // psum   [4][64] f32          :  1024 B
#define LDSTOT 75776

__global__ __launch_bounds__(512, 2) void k3_edge_f16(
    const float* __restrict__ Y, const unsigned short* __restrict__ Wf,
    const float* __restrict__ bih0, const float* __restrict__ bhh0,
    const float* __restrict__ bih1, const float* __restrict__ bhh1,
    const float* __restrict__ clsW, const float* __restrict__ clsb,
    float* __restrict__ adj) {
  extern __shared__ char sm[];
  _Float16* Aq = (_Float16*)(sm + LDSA);
  _Float16* N0 = (_Float16*)(sm + LDSN0);
  _Float16* N1 = (_Float16*)(sm + LDSN1);
  float* psum = (float*)(sm + LDSPS);

  const int tid = threadIdx.x;
  const int w = tid >> 6, l = tid & 63;
  const int mg = w & 1, ng = w >> 1;
  const int colL = l & 15, q = l >> 4;
  const int node0 = blockIdx.x * 64;

  for (int i = tid; i < 2048; i += 512) ((unsigned*)(sm + LDSA))[i] = 0u;
  for (int i = tid; i < 8192; i += 512) ((unsigned*)(sm + LDSN1))[i] = 0u;
  for (int i = tid; i < 8192; i += 512) {
    int nn = i >> 7, k = i & 127;
    float v = Y[(size_t)(node0 + nn) * 128 + k];
    N0[sw(nn, k, 128)] = (_Float16)v;
  }

  f16x8 Wr[2][14];
#pragma unroll
  for (int nt = 0; nt < 2; ++nt)
#pragma unroll
    for (int kc = 0; kc < 14; ++kc)
      Wr[nt][kc] =
          ((const f16x8*)Wf)[(size_t)(((2 * ng + nt) * 14) + kc) * 64 + l];

  float b0v[2], b1v[2], cwv[2];
#pragma unroll
  for (int nt = 0; nt < 2; ++nt) {
    int cg = (2 * ng + nt) * 16 + colL;
    b0v[nt] = bih0[cg] + bhh0[cg];
    b1v[nt] = bih1[cg] + bhh1[cg];
    cwv[nt] = clsW[cg];
  }
  const float cbias = clsb[0];
  const int ipos = (node0 & 511) + l;
  const int mval = min(ipos, 64);
  const int badj = node0 >> 9;

  __syncthreads();

  int p = 0;
  for (int step = 0; step < 64; ++step) {
    _Float16* n0rd = N0 + p * 8192;
    _Float16* n0wr = N0 + (p ^ 1) * 8192;
    _Float16* n1rd = N1 + p * 8192;
    _Float16* n1wr = N1 + (p ^ 1) * 8192;

    f32x4 acc[2][2];
#pragma unroll
    for (int mt = 0; mt < 2; ++mt)
#pragma unroll
      for (int nt = 0; nt < 2; ++nt)
        acc[mt][nt] = (f32x4){b0v[nt], b0v[nt], b0v[nt], b0v[nt]};
#pragma unroll
    for (int kc = 0; kc < 6; ++kc) {
      f16x8 ah[2];
#pragma unroll
      for (int mt = 0; mt < 2; ++mt) {
        int row = mg * 32 + mt * 16 + colL;
        if (kc < 2) {
          int gk = kc * 4 + q;
          ah[mt] = *(const f16x8*)&Aq[row * 64 + ((gk ^ (row & 7)) << 3)];
        } else {
          int gk = (kc - 2) * 4 + q;
          ah[mt] = *(const f16x8*)&n0rd[row * 128 + ((gk ^ (row & 7)) << 3)];
        }
      }
#pragma unroll
      for (int mt = 0; mt < 2; ++mt)
#pragma unroll
        for (int nt = 0; nt < 2; ++nt)
          acc[mt][nt] = MFMAH(ah[mt], Wr[nt][kc], acc[mt][nt]);
    }
#pragma unroll
    for (int mt = 0; mt < 2; ++mt)
#pragma unroll
      for (int nt = 0; nt < 2; ++nt)
#pragma unroll
        for (int rg = 0; rg < 4; ++rg) {
          float v = fast_tanh(acc[mt][nt][rg]);
          int row = mg * 32 + mt * 16 + q * 4 + rg;
          int col = (2 * ng + nt) * 16 + colL;
          n0wr[sw(row, col, 128)] = (_Float16)v;
        }
    __syncthreads();  // bar A: n0 complete

    f32x4 acc2[2][2];
#pragma unroll
    for (int mt = 0; mt < 2; ++mt)
#pragma unroll
      for (int nt = 0; nt < 2; ++nt)
        acc2[mt][nt] = (f32x4){b1v[nt], b1v[nt], b1v[nt], b1v[nt]};
#pragma unroll
    for (int kc = 0; kc < 8; ++kc) {
      const _Float16* src = (kc < 4) ? n0wr : n1rd;
      int gk = (kc & 3) * 4 + q;
      f16x8 ah[2];
#pragma unroll
      for (int mt = 0; mt < 2; ++mt) {
        int row = mg * 32 + mt * 16 + colL;
        ah[mt] = *(const f16x8*)&src[row * 128 + ((gk ^ (row & 7)) << 3)];
      }
#pragma unroll
      for (int mt = 0; mt < 2; ++mt)
#pragma unroll
        for (int nt = 0; nt < 2; ++nt)
          acc2[mt][nt] = MFMAH(ah[mt], Wr[nt][6 + kc], acc2[mt][nt]);
    }
    float pa[2][4];
#pragma unroll
    for (int mt = 0; mt < 2; ++mt)
#pragma unroll
      for (int rg = 0; rg < 4; ++rg) pa[mt][rg] = 0.f;
#pragma unroll
    for (int mt = 0; mt < 2; ++mt)
#pragma unroll
      for (int nt = 0; nt < 2; ++nt)
#pragma unroll
        for (int rg = 0; rg < 4; ++rg) {
          float v = fast_tanh(acc2[mt][nt][rg]);
          pa[mt][rg] += cwv[nt] * v;
          int row = mg * 32 + mt * 16 + q * 4 + rg;
          int col = (2 * ng + nt) * 16 + colL;
          n1wr[sw(row, col, 128)] = (_Float16)v;
        }
#pragma unroll
    for (int mt = 0; mt < 2; ++mt)
#pragma unroll
      for (int rg = 0; rg < 4; ++rg) {
        float s = pa[mt][rg];
        s += __shfl_xor(s, 1);
        s += __shfl_xor(s, 2);
        s += __shfl_xor(s, 4);
        s += __shfl_xor(s, 8);
        pa[mt][rg] = s;
      }
#pragma unroll
    for (int ii = 0; ii < 8; ++ii)
      if (colL == ii) {
        int row = mg * 32 + (ii >> 2) * 16 + q * 4 + (ii & 3);
        psum[ng * 64 + row] = pa[ii >> 2][ii & 3];
      }
    __syncthreads();  // bar B: psum + n1 complete

    {
      float s = cbias + psum[l] + psum[64 + l] + psum[128 + l] +
                psum[192 + l];
      float sg = fast_sigmoid(s);
      if (step < mval)
        Aq[l * 64 + ((((step >> 3) ^ (l & 7)) << 3) | (step & 7))] =
            (_Float16)sg;
    }
    p ^= 1;
  }
  __syncthreads();

  // ---- epilogue: write FULL 512x64 adj tile (zeros + band), coalesced.
  // lane: qd = col quad (4 nodes), rg4 = row within 4-row group.
  {
    const int qd = l & 15;
    const int rg4 = l >> 4;
    const int ii0 = node0 & 511;
    for (int rb = 0; rb < 64; rb += 4) {
      int r = w * 64 + rb + rg4;
      float4 v;
      float* vp = (float*)&v;
#pragma unroll
      for (int c = 0; c < 4; ++c) {
        int n = qd * 4 + c;
        int ii = ii0 + n;
        int base = (ii - 64 > 0) ? ii - 64 : 0;
        int mv = min(ii, 64);
        int k = r - base;
        float val = 0.f;
        if (k >= 0 && k < mv) val = (float)Aq[sw(n, k, 64)];
        vp[c] = val;
      }
      *(float4*)&adj[((size_t)badj * 512 + r) * 512 + ii0 + qd * 4] = v;
    }
  }
}

extern "C" void kernel_launch(void* const* d_in, const int* in_sizes, int n_in,
                              void* d_out, int out_size, void* d_ws,
                              size_t ws_size, hipStream_t stream) {
  const float* x = (const float*)d_in[0];
  const int* mask = (const int*)d_in[1];
  const float* gWih0 = (const float*)d_in[2];
  const float* gWhh0 = (const float*)d_in[3];
  const float* gbih0 = (const float*)d_in[4];
  const float* gbhh0 = (const float*)d_in[5];
  const float* gWih1 = (const float*)d_in[6];
  const float* gWhh1 = (const float*)d_in[7];
  const float* gbih1 = (const float*)d_in[8];
  const float* gbhh1 = (const float*)d_in[9];
  const float* eWih0 = (const float*)d_in[10];
  const float* eWhh0 = (const float*)d_in[11];
  const float* ebih0 = (const float*)d_in[12];
  const float* ebhh0 = (const float*)d_in[13];
  const float* eWih1 = (const float*)d_in[14];
  const float* eWhh1 = (const float*)d_in[15];
  const float* ebih1 = (const float*)d_in[16];
  const float* ebhh1 = (const float*)d_in[17];
  const float* clsW = (const float*)d_in[18];
  const float* clsb = (const float*)d_in[19];
  float* out = (float*)d_out;
  float* Y = out;
  float* adj = out + YSZ;
  float* P0 = adj;  // scratch overlay in adj region; k3 overwrites all of adj

  unsigned short* Wf = (unsigned short*)d_ws;
  hipLaunchKernelGGL(k0_prep, dim3(28), dim3(256), 0, stream, eWih0, eWhh0,
                     eWih1, eWhh1, Wf);
  hipLaunchKernelGGL(k1_gemm, dim3(256), dim3(256), 0, stream, x, gWih0,
                     gbih0, gbhh0, P0);
  hipLaunchKernelGGL(k2_v7, dim3(4), dim3(512), 0, stream, P0, gWhh0, gWih1,
                     gWhh1, gbih1, gbhh1, mask, Y);
  hipFuncSetAttribute(reinterpret_cast<const void*>(k3_edge_f16),
                      hipFuncAttributeMaxDynamicSharedMemorySize, LDSTOT);
  hipLaunchKernelGGL(k3_edge_f16, dim3(512), dim3(512), LDSTOT, stream, Y,
                     Wf, ebih0, ebhh0, ebih1, ebhh1, clsW, clsb, adj);
}